// Round 17
// baseline (880.739 us; speedup 1.0000x reference)
//
#include <hip/hip_runtime.h>
#include <hip/hip_bf16.h>

typedef __hip_bfloat16 bf16;
typedef unsigned short u16;
typedef __attribute__((ext_vector_type(8))) short bf16x8;
typedef __attribute__((ext_vector_type(4))) float f32x4;

__device__ __forceinline__ float b2f(bf16 v) { return __bfloat162float(v); }
__device__ __forceinline__ float b2f_u(u16 h) {
    union { unsigned u; float f; } c; c.u = ((unsigned)h) << 16; return c.f;
}
__device__ __forceinline__ u16 f2b(float v) {
    union { bf16 b; u16 u; } c; c.b = __float2bfloat16(v); return c.u;
}
__device__ __forceinline__ float lrelu(float v) { return v >= 0.f ? v : 0.2f * v; }
__device__ __forceinline__ float ldin(const void* p, size_t i, int isbf) {
    if (isbf) return b2f(((const bf16*)p)[i]);
    return ((const float*)p)[i];
}
// LDS act tile [pl][64 ci] bf16: chunk XOR-swizzled by (pl&7) -> conflict-free.
__device__ __forceinline__ bf16x8 frag(const u16* t, int pl, int chunk) {
    return *(const bf16x8*)(t + pl * 64 + ((chunk ^ (pl & 7)) << 3));
}
// async global->LDS, 16B per lane; lds dest is wave-uniform base + lane*16.
__device__ __forceinline__ void glds16(const u16* g, u16* l) {
    __builtin_amdgcn_global_load_lds(
        (const __attribute__((address_space(1))) unsigned int*)g,
        (__attribute__((address_space(3))) unsigned int*)l, 16, 0, 0);
}

// ---------------------------------------------------------------------------
// Probe: bf16 vs fp32 input detection.
// ---------------------------------------------------------------------------
__global__ __launch_bounds__(256)
void probe_kernel(const void* __restrict__ x, int* __restrict__ flag) {
    const int tid = threadIdx.x;
    __shared__ int bad;
    if (tid == 0) bad = 0;
    __syncthreads();
    const unsigned short* h = (const unsigned short*)x;
    for (int k = tid; k < 512; k += 256) {
        const unsigned e = (h[k] >> 7) & 0xFFu;
        if (e < 100u || e > 140u) atomicAdd(&bad, 1);
    }
    __syncthreads();
    if (tid == 0) flag[0] = (bad == 0) ? 1 : 0;
}

// ---------------------------------------------------------------------------
// Transpose: x [b][64ci][y][x] -> xrw [b][y][x][64ci] bf16 (hi; lo in fp32).
// (lo plane used only by conv2's full-precision shortcut.)
// ---------------------------------------------------------------------------
__global__ __launch_bounds__(256)
void transpose_kernel(const void* __restrict__ x, u16* __restrict__ xrw,
                      u16* __restrict__ xrl, const int* __restrict__ flag) {
    __shared__ u16 hA[4096];
    __shared__ u16 lA[4096];
    const int isbf = flag[0];
    const int xb = blockIdx.x;   // 0..3
    const int y  = blockIdx.y;   // 0..255
    const int b  = blockIdx.z;   // 0..7
    const int t  = threadIdx.x;
    const int gx0 = xb << 6;

    if (isbf) {
        const u16* xp = (const u16*)x;
        for (int i = 0; i < 2; ++i) {
            const int chunk = i * 256 + t;
            const int ci = chunk >> 3, xc = chunk & 7;
            bf16x8 v = *(const bf16x8*)(xp + (((size_t)b * 64 + ci) << 16) +
                                        ((size_t)y << 8) + gx0 + xc * 8);
#pragma unroll
            for (int j = 0; j < 8; ++j) {
                const int pl = xc * 8 + j;
                hA[pl * 64 + (ci ^ (((pl >> 3) & 7) << 3))] = (u16)v[j];
            }
        }
    } else {
        const float* xp = (const float*)x;
        for (int i = 0; i < 4; ++i) {
            const int chunk = i * 256 + t;
            const int ci = chunk >> 4, x4 = chunk & 15;
            f32x4 v = *(const f32x4*)(xp + (((size_t)b * 64 + ci) << 16) +
                                      ((size_t)y << 8) + gx0 + x4 * 4);
#pragma unroll
            for (int j = 0; j < 4; ++j) {
                const int pl = x4 * 4 + j;
                const int a = pl * 64 + (ci ^ (((pl >> 3) & 7) << 3));
                const u16 h = f2b(v[j]);
                hA[a] = h;
                lA[a] = f2b(v[j] - b2f_u(h));
            }
        }
    }
    __syncthreads();
    for (int i = 0; i < 2; ++i) {
        const int chunk = i * 256 + t;
        const int xl = chunk >> 3, co = chunk & 7;
        const int a = xl * 64 + ((co ^ ((xl >> 3) & 7)) << 3);
        const size_t dst = (((((size_t)b << 16) + ((size_t)y << 8)) + gx0 + xl) << 6) + co * 8;
        *(bf16x8*)(xrw + dst) = *(const bf16x8*)(hA + a);
        if (!isbf) *(bf16x8*)(xrl + dst) = *(const bf16x8*)(lA + a);
    }
}

// ---------------------------------------------------------------------------
// Weights: styles + demod; effective weights (bf16 hi ONLY) stored as
// per-TAP 16 KB slabs:
//   w1x: [b][9 tap][128 oc][8 ch x 16B]   ch = ((g<<1)|cs) ^ (oc&7)
//   w2x: [b][18 tap][128 oc][8 ch x 16B]  (tap = cc*9 + t; ci frag-permuted)
// ---------------------------------------------------------------------------
__global__ __launch_bounds__(256)
void weights_kernel(const void* __restrict__ s,
                    const void* __restrict__ a1w, const void* __restrict__ a1b,
                    const void* __restrict__ w1,
                    const void* __restrict__ a2w, const void* __restrict__ a2b,
                    const void* __restrict__ w2,
                    const void* __restrict__ scw_in,
                    u16* __restrict__ w1x, u16* __restrict__ w2x,
                    u16* __restrict__ scx, const int* __restrict__ flag) {
    const int isbf = flag[0];
    const int b = blockIdx.x;
    const int part = blockIdx.y;   // 0..3
    const int tid = threadIdx.x;
    __shared__ float sb[64];
    __shared__ float st1[64];
    __shared__ float st2[128];
    __shared__ float d1[128];
    __shared__ float d2[128];

    if (tid < 64) sb[tid] = ldin(s, b * 64 + tid, isbf);
    __syncthreads();

    if (tid < 64) {
        float a = ldin(a1b, tid, isbf) + 1.f;
        for (int j = 0; j < 64; ++j) a += sb[j] * ldin(a1w, tid * 64 + j, isbf);
        st1[tid] = a;
    }
    if (tid >= 128) {
        const int i = tid - 128;
        float a = ldin(a2b, i, isbf) + 1.f;
        for (int j = 0; j < 64; ++j) a += sb[j] * ldin(a2w, i * 64 + j, isbf);
        st2[i] = a;
    }
    __syncthreads();

    if (tid < 128) {
        float acc = 0.f;
        if (isbf) {
            const u16* wp = (const u16*)w1 + tid * 576;
            for (int k = 0; k < 72; ++k) {
                bf16x8 v = *(const bf16x8*)(wp + k * 8);
#pragma unroll
                for (int e = 0; e < 8; ++e) {
                    const int r = k * 8 + e;
                    const float f = b2f_u((u16)v[e]) * st1[r / 9];
                    acc += f * f;
                }
            }
        } else {
            for (int i = 0; i < 64; ++i) {
                const float st = st1[i];
                for (int t = 0; t < 9; ++t) {
                    const float v = ldin(w1, (tid * 64 + i) * 9 + t, isbf) * st;
                    acc += v * v;
                }
            }
        }
        d1[tid] = rsqrtf(acc + 1e-8f);
    } else {
        const int o = tid - 128;
        float acc = 0.f;
        if (isbf) {
            const u16* wp = (const u16*)w2 + o * 1152;
            for (int k = 0; k < 144; ++k) {
                bf16x8 v = *(const bf16x8*)(wp + k * 8);
#pragma unroll
                for (int e = 0; e < 8; ++e) {
                    const int r = k * 8 + e;
                    const float f = b2f_u((u16)v[e]) * st2[r / 9];
                    acc += f * f;
                }
            }
        } else {
            for (int i = 0; i < 128; ++i) {
                const float st = st2[i];
                for (int t = 0; t < 9; ++t) {
                    const float v = ldin(w2, (o * 128 + i) * 9 + t, isbf) * st;
                    acc += v * v;
                }
            }
        }
        d2[o] = rsqrtf(acc + 1e-8f);
    }
    __syncthreads();

    // w1x slabs (hi only, per-tap)
    for (int idx = part * 18432 + tid; idx < (part + 1) * 18432; idx += 256) {
        const int o = idx / 576;
        const int r = idx - o * 576;
        const int i = r / 9;
        const int t = r - i * 9;
        const float w = ldin(w1, idx, isbf) * st1[i] * d1[o];
        const int cs = i >> 5, g = (i >> 3) & 3, e = i & 7;
        const size_t base = (((size_t)b * 9 + t) << 13) + o * 64;
        w1x[base + (((((g << 1) | cs)) ^ (o & 7)) << 3) + e] = f2b(w);
    }
    // w2x slabs (hi only, per-tap, ci fragment-permuted)
    for (int idx = part * 36864 + tid; idx < (part + 1) * 36864; idx += 256) {
        const int o = idx / 1152;
        const int r = idx - o * 1152;
        const int i = r / 9;
        const int t = r - i * 9;
        const float w = ldin(w2, idx, isbf) * st2[i] * d2[o];
        const int ip = (i & 64) + (((i >> 2) & 3) << 4) + (((i >> 4) & 3) << 2) + (i & 3);
        const int cc = ip >> 6, p6 = ip & 63;
        const int cs = p6 >> 5, g = (p6 >> 3) & 3, e = p6 & 7;
        const int tap = cc * 9 + t;
        const size_t base = (((size_t)b * 18 + tap) << 13) + o * 64;
        w2x[base + (((((g << 1) | cs)) ^ (o & 7)) << 3) + e] = f2b(w);
    }
    // shortcut [128 oc][8 ch][hi8|lo8] (kept full precision)
    if (b == 0 && part == 0) {
        for (int idx = tid; idx < 8192; idx += 256) {
            const int o = idx >> 6, i = idx & 63;
            const float w = ldin(scw_in, idx, isbf);
            const u16 h = f2b(w);
            const size_t dst = ((size_t)o << 7) + ((i >> 3) << 4) + (i & 7);
            scx[dst] = h;
            scx[dst + 8] = f2b(w - b2f_u(h));
        }
    }
}

// ---------------------------------------------------------------------------
// Conv1 (512 thr, 8 waves, acc[4][4]): hi-only input, 9 tap-phases.
// 3-slab DMA rotation with COUNTED vmcnt(2): next-phase loads stay in flight
// across the barrier (T4). 90.6 KB LDS -> 1 block/CU.
// ---------------------------------------------------------------------------
__global__ __launch_bounds__(512, 2)
void conv1_mfma(const u16* __restrict__ xrw,
                const void* __restrict__ noise, const void* __restrict__ nwp,
                const u16* __restrict__ w1x, u16* __restrict__ h1t,
                const int* __restrict__ flag) {
    __shared__ __align__(16) u16 lds[324 * 64 + 3 * 8192];
    u16* tile = lds;
    const int isbf = flag[0];
    const int n = blockIdx.x + (blockIdx.y << 4) + (blockIdx.z << 8);
    const int sw = (n & 7) * 256 + (n >> 3);         // same-b -> same XCD
    const int b = sw >> 8;
    const int by = (sw >> 4) & 15;
    const int bx = sw & 15;
    const int gx0 = bx << 4, gy0 = by << 4;
    const int tid = threadIdx.x;
    const int lane = tid & 63;
    const int wv = tid >> 6;
    const int wm = wv >> 2, wn = wv & 3;
    const int l15 = lane & 15, g = lane >> 4;
    const int swh = (((g << 1) ^ (l15 & 7)) << 3);            // cs0 weights
    const int swl = ((((g << 1) | 1) ^ (l15 & 7)) << 3);      // cs1 weights
    const int plb = wn * 72 + l15;                   // wn*4 rows * 18 + l15

    auto slab_at = [&](int i) -> u16* { return lds + 20736 + i * 8192; };

    auto stage_act = [&]() {
        for (int idx = tid; idx < 2592; idx += 512) {
            const int pl = idx >> 3, c = idx & 7;
            const int row = pl / 18, col = pl - row * 18;
            const int gy = gy0 - 1 + row, gx = gx0 - 1 + col;
            u16 ov[8];
            if ((unsigned)gy < 256u && (unsigned)gx < 256u) {
                const size_t ofs = ((((size_t)b << 16) + (gy << 8) + gx) << 6) + c * 8;
                bf16x8 vh = *(const bf16x8*)(xrw + ofs);
#pragma unroll
                for (int j = 0; j < 8; ++j) {
                    u16 h = (u16)vh[j];
                    if (h & 0x8000u) h = f2b(0.2f * b2f_u(h));
                    ov[j] = h;
                }
            } else {
#pragma unroll
                for (int j = 0; j < 8; ++j) ov[j] = 0;
            }
            *(bf16x8*)(tile + pl * 64 + ((c ^ (pl & 7)) << 3)) = *(bf16x8*)ov;
        }
    };

    auto stageW = [&](int tap, u16* sl) {
        const u16* src = w1x + (((size_t)b * 9 + tap) << 13) + wv * 1024 + lane * 8;
        u16* dst = sl + wv * 1024;
        glds16(src, dst);
        glds16(src + 512, dst + 512);
    };

    f32x4 acc[4][4];
#pragma unroll
    for (int i = 0; i < 4; ++i)
#pragma unroll
        for (int j = 0; j < 4; ++j) acc[i][j] = (f32x4){0.f, 0.f, 0.f, 0.f};

    auto mm = [&](int q, const u16* sl) {
        const int kh = q / 3, kw = q - kh * 3;
        // cs = 0 half
        {
            bf16x8 bh[4];
#pragma unroll
            for (int fn = 0; fn < 4; ++fn)
                bh[fn] = frag(tile, plb + (fn + kh) * 18 + kw, g);
            bf16x8 H[4];
#pragma unroll
            for (int fm = 0; fm < 4; ++fm)
                H[fm] = *(const bf16x8*)(sl + (wm * 64 + fm * 16 + l15) * 64 + swh);
            __builtin_amdgcn_s_setprio(1);
#pragma unroll
            for (int fm = 0; fm < 4; ++fm)
#pragma unroll
                for (int fn = 0; fn < 4; ++fn)
                    acc[fm][fn] = __builtin_amdgcn_mfma_f32_16x16x32_bf16(H[fm], bh[fn], acc[fm][fn], 0, 0, 0);
            __builtin_amdgcn_s_setprio(0);
        }
        // cs = 1 half
        {
            bf16x8 bh[4];
#pragma unroll
            for (int fn = 0; fn < 4; ++fn)
                bh[fn] = frag(tile, plb + (fn + kh) * 18 + kw, 4 + g);
            bf16x8 L[4];
#pragma unroll
            for (int fm = 0; fm < 4; ++fm)
                L[fm] = *(const bf16x8*)(sl + (wm * 64 + fm * 16 + l15) * 64 + swl);
            __builtin_amdgcn_s_setprio(1);
#pragma unroll
            for (int fm = 0; fm < 4; ++fm)
#pragma unroll
                for (int fn = 0; fn < 4; ++fn)
                    acc[fm][fn] = __builtin_amdgcn_mfma_f32_16x16x32_bf16(L[fm], bh[fn], acc[fm][fn], 0, 0, 0);
            __builtin_amdgcn_s_setprio(0);
        }
    };

    stage_act();
    stageW(0, slab_at(0));
    stageW(1, slab_at(1));
    __syncthreads();                      // act ready (drains prologue stages)

#pragma unroll 1
    for (int q = 0; q < 9; ++q) {
        if (q + 1 < 9) asm volatile("s_waitcnt vmcnt(2)" ::: "memory");
        else           asm volatile("s_waitcnt vmcnt(0)" ::: "memory");
        __builtin_amdgcn_s_barrier();
        __builtin_amdgcn_sched_barrier(0);
        if (q + 2 < 9) stageW(q + 2, slab_at((q + 2) % 3));
        mm(q, slab_at(q % 3));
    }

    const float nwv = ldin(nwp, 0, isbf);
#pragma unroll
    for (int fn = 0; fn < 4; ++fn) {
        const int gy = gy0 + wn * 4 + fn;
        const int gx = gx0 + l15;
        const float nv = nwv * ldin(noise, ((size_t)b << 16) + (gy << 8) + gx, isbf);
        unsigned wd[8];
#pragma unroll
        for (int fm = 0; fm < 4; ++fm) {
            wd[fm * 2]     = (unsigned)f2b(lrelu(acc[fm][fn][0] + nv)) |
                             ((unsigned)f2b(lrelu(acc[fm][fn][1] + nv)) << 16);
            wd[fm * 2 + 1] = (unsigned)f2b(lrelu(acc[fm][fn][2] + nv)) |
                             ((unsigned)f2b(lrelu(acc[fm][fn][3] + nv)) << 16);
        }
        u16* dst = h1t + ((((size_t)b << 16) + (gy << 8) + gx) << 7) + wm * 64 + g * 16;
        *(uint4*)dst = make_uint4(wd[0], wd[1], wd[2], wd[3]);
        *(uint4*)(dst + 8) = make_uint4(wd[4], wd[5], wd[6], wd[7]);
    }
}

// ---------------------------------------------------------------------------
// Conv2 (512 thr): conv3x3(h1, w2-hi) + full-precision 1x1 shortcut + noise,
// /sqrt2. 18 tap-phases, 3-slab counted-vmcnt pipeline; full drain once at
// the q==9 act restage; shortcut aliases the slab area after the loop.
// ---------------------------------------------------------------------------
__global__ __launch_bounds__(512, 2)
void conv2_mfma(const u16* __restrict__ h1t, const u16* __restrict__ xrw,
                const u16* __restrict__ xrl,
                const void* __restrict__ noise, const void* __restrict__ nwp,
                const u16* __restrict__ w2x, const u16* __restrict__ scx,
                void* __restrict__ out, const int* __restrict__ flag) {
    __shared__ __align__(16) u16 lds[324 * 64 + 3 * 8192];
    u16* tile = lds;
    const int isbf = flag[0];
    const int n = blockIdx.x + (blockIdx.y << 4) + (blockIdx.z << 8);
    const int sw = (n & 7) * 256 + (n >> 3);
    const int b = sw >> 8;
    const int by = (sw >> 4) & 15;
    const int bx = sw & 15;
    const int gx0 = bx << 4, gy0 = by << 4;
    const int tid = threadIdx.x;
    const int lane = tid & 63;
    const int wv = tid >> 6;
    const int wm = wv >> 2, wn = wv & 3;
    const int l15 = lane & 15, g = lane >> 4;
    const int swh = (((g << 1) ^ (l15 & 7)) << 3);
    const int swl = ((((g << 1) | 1) ^ (l15 & 7)) << 3);
    const int plb = wn * 72 + l15;
    const bf16x8 z8 = {0, 0, 0, 0, 0, 0, 0, 0};

    auto slab_at = [&](int i) -> u16* { return lds + 20736 + i * 8192; };
    u16* tsc = lds + 20736;              // 48 KB slab area, 32 KB used

    auto stage_cc = [&](int cc) {
        for (int idx = tid; idx < 2592; idx += 512) {
            const int pl = idx >> 3, c = idx & 7;
            const int row = pl / 18, col = pl - row * 18;
            const int gy = gy0 - 1 + row, gx = gx0 - 1 + col;
            bf16x8 v = z8;
            if ((unsigned)gy < 256u && (unsigned)gx < 256u)
                v = *(const bf16x8*)(h1t + ((((size_t)b << 16) + (gy << 8) + gx) << 7) + cc * 64 + c * 8);
            *(bf16x8*)(tile + pl * 64 + ((c ^ (pl & 7)) << 3)) = v;
        }
    };
    auto stageW = [&](int tap, u16* sl) {
        const u16* src = w2x + (((size_t)b * 18 + tap) << 13) + wv * 1024 + lane * 8;
        u16* dst = sl + wv * 1024;
        glds16(src, dst);
        glds16(src + 512, dst + 512);
    };

    f32x4 acc[4][4];
#pragma unroll
    for (int i = 0; i < 4; ++i)
#pragma unroll
        for (int j = 0; j < 4; ++j) acc[i][j] = (f32x4){0.f, 0.f, 0.f, 0.f};

    auto mm = [&](int q, const u16* sl) {
        const int qq = q % 9;
        const int kh = qq / 3, kw = qq - kh * 3;
        {
            bf16x8 bh[4];
#pragma unroll
            for (int fn = 0; fn < 4; ++fn)
                bh[fn] = frag(tile, plb + (fn + kh) * 18 + kw, g);
            bf16x8 H[4];
#pragma unroll
            for (int fm = 0; fm < 4; ++fm)
                H[fm] = *(const bf16x8*)(sl + (wm * 64 + fm * 16 + l15) * 64 + swh);
            __builtin_amdgcn_s_setprio(1);
#pragma unroll
            for (int fm = 0; fm < 4; ++fm)
#pragma unroll
                for (int fn = 0; fn < 4; ++fn)
                    acc[fm][fn] = __builtin_amdgcn_mfma_f32_16x16x32_bf16(H[fm], bh[fn], acc[fm][fn], 0, 0, 0);
            __builtin_amdgcn_s_setprio(0);
        }
        {
            bf16x8 bh[4];
#pragma unroll
            for (int fn = 0; fn < 4; ++fn)
                bh[fn] = frag(tile, plb + (fn + kh) * 18 + kw, 4 + g);
            bf16x8 L[4];
#pragma unroll
            for (int fm = 0; fm < 4; ++fm)
                L[fm] = *(const bf16x8*)(sl + (wm * 64 + fm * 16 + l15) * 64 + swl);
            __builtin_amdgcn_s_setprio(1);
#pragma unroll
            for (int fm = 0; fm < 4; ++fm)
#pragma unroll
                for (int fn = 0; fn < 4; ++fn)
                    acc[fm][fn] = __builtin_amdgcn_mfma_f32_16x16x32_bf16(L[fm], bh[fn], acc[fm][fn], 0, 0, 0);
            __builtin_amdgcn_s_setprio(0);
        }
    };

    stage_cc(0);
    stageW(0, slab_at(0));
    stageW(1, slab_at(1));
    __syncthreads();

#pragma unroll 1
    for (int q = 0; q < 18; ++q) {
        if (q == 9) {                    // restage cc1 act half (full drain)
            asm volatile("s_waitcnt vmcnt(0)" ::: "memory");
            __syncthreads();
            stage_cc(1);
            __syncthreads();
        }
        if (q + 1 < 18) asm volatile("s_waitcnt vmcnt(2)" ::: "memory");
        else            asm volatile("s_waitcnt vmcnt(0)" ::: "memory");
        __builtin_amdgcn_s_barrier();
        __builtin_amdgcn_sched_barrier(0);
        if (q + 2 < 18) stageW(q + 2, slab_at((q + 2) % 3));
        mm(q, slab_at(q % 3));
    }

    // ---- 1x1 shortcut: stage raw x into tsc (aliases slabs) ----
    auto stage_sc = [&](const u16* src) {
#pragma unroll
        for (int k = 0; k < 4; ++k) {
            const int idx = tid + (k << 9);
            const int pl = idx >> 3, c = idx & 7;
            const int gy = gy0 + (pl >> 4), gx = gx0 + (pl & 15);
            bf16x8 v = *(const bf16x8*)(src + ((((size_t)b << 16) + (gy << 8) + gx) << 6) + c * 8);
            *(bf16x8*)(tsc + pl * 64 + ((c ^ (pl & 7)) << 3)) = v;
        }
    };
    auto sc_phases = [&](int dolo) {
        const u16* sB = scx + (wm * 64 + l15) * 128 + g * 16;
#pragma unroll
        for (int cs = 0; cs < 2; ++cs) {
            bf16x8 bh[4];
#pragma unroll
            for (int fn = 0; fn < 4; ++fn)
                bh[fn] = frag(tsc, (wn * 4 + fn) * 16 + l15, cs * 4 + g);
            const u16* at = sB + cs * 64;
            __builtin_amdgcn_s_setprio(1);
#pragma unroll
            for (int fm = 0; fm < 4; ++fm) {
                const bf16x8 ah = *(const bf16x8*)(at + fm * 2048);
#pragma unroll
                for (int fn = 0; fn < 4; ++fn)
                    acc[fm][fn] = __builtin_amdgcn_mfma_f32_16x16x32_bf16(ah, bh[fn], acc[fm][fn], 0, 0, 0);
                if (dolo) {
                    const bf16x8 al = *(const bf16x8*)(at + fm * 2048 + 8);
#pragma unroll
                    for (int fn = 0; fn < 4; ++fn)
                        acc[fm][fn] = __builtin_amdgcn_mfma_f32_16x16x32_bf16(al, bh[fn], acc[fm][fn], 0, 0, 0);
                }
            }
            __builtin_amdgcn_s_setprio(0);
        }
    };

    __syncthreads();          // all waves done with slab reads before overwrite
    stage_sc(xrw);
    __syncthreads();
    sc_phases(1);
    if (!isbf) {
        __syncthreads();
        stage_sc(xrl);
        __syncthreads();
        sc_phases(0);
    }

    const float nwv = ldin(nwp, 0, isbf);
    const float kk = 0.70710678118654752f;
    if (isbf) {
        bf16* op = (bf16*)out;
#pragma unroll
        for (int fn = 0; fn < 4; ++fn) {
            const int gy = gy0 + wn * 4 + fn;
            const int gx = gx0 + l15;
            const float nv = nwv * ldin(noise, ((size_t)b << 16) + (gy << 8) + gx, isbf);
#pragma unroll
            for (int fm = 0; fm < 4; ++fm) {
                const int oc = wm * 64 + fm * 16 + g * 4;
#pragma unroll
                for (int r = 0; r < 4; ++r) {
                    const float v = (acc[fm][fn][r] + nv) * kk;
                    op[(((size_t)b * 128 + oc + r) << 16) + (gy << 8) + gx] = __float2bfloat16(v);
                }
            }
        }
    } else {
        float* op = (float*)out;
#pragma unroll
        for (int fn = 0; fn < 4; ++fn) {
            const int gy = gy0 + wn * 4 + fn;
            const int gx = gx0 + l15;
            const float nv = nwv * ldin(noise, ((size_t)b << 16) + (gy << 8) + gx, isbf);
#pragma unroll
            for (int fm = 0; fm < 4; ++fm) {
                const int oc = wm * 64 + fm * 16 + g * 4;
#pragma unroll
                for (int r = 0; r < 4; ++r) {
                    const float v = (acc[fm][fn][r] + nv) * kk;
                    op[(((size_t)b * 128 + oc + r) << 16) + (gy << 8) + gx] = v;
                }
            }
        }
    }
}

extern "C" void kernel_launch(void* const* d_in, const int* in_sizes, int n_in,
                              void* d_out, int out_size, void* d_ws, size_t ws_size,
                              hipStream_t stream) {
    const void* x     = d_in[0];
    const void* s     = d_in[1];
    const void* noise = d_in[2];
    const void* a1w   = d_in[3];
    const void* a1b   = d_in[4];
    const void* w1    = d_in[5];
    const void* a2w   = d_in[6];
    const void* a2b   = d_in[7];
    const void* w2    = d_in[8];
    const void* nw    = d_in[9];
    const void* scw   = d_in[10];

    // ws layout (bytes):
    //   flag      256
    //   w1x       1,179,648   ([8][9 tap][16 KB slab], hi only)
    //   w2x       2,359,296   ([8][18 tap][16 KB slab], hi only)
    //   scx          32,768
    //   h1t     134,217,728   ([8][256][256][128] bf16, permuted oc)
    //   xrw      67,108,864   ([8][256][256][64] bf16, raw hi)
    //   xrl      67,108,864   (lo plane; fp32 mode, shortcut only)
    char* p = (char*)d_ws;
    int* flag = (int*)p;   p += 256;
    u16* w1x = (u16*)p;    p += 1179648;
    u16* w2x = (u16*)p;    p += 2359296;
    u16* scx = (u16*)p;    p += 32768;
    u16* h1t = (u16*)p;    p += 134217728;
    u16* xrw = (u16*)p;    p += 67108864;
    u16* xrl = (u16*)p;

    probe_kernel<<<dim3(1), dim3(256), 0, stream>>>(x, flag);
    transpose_kernel<<<dim3(4, 256, 8), dim3(256), 0, stream>>>(x, xrw, xrl, flag);
    weights_kernel<<<dim3(8, 4), dim3(256), 0, stream>>>(s, a1w, a1b, w1, a2w, a2b, w2,
                                                         scw, w1x, w2x, scx, flag);
    dim3 grid(16, 16, 8);
    conv1_mfma<<<grid, dim3(512), 0, stream>>>(xrw, noise, nw, w1x, h1t, flag);
    conv2_mfma<<<grid, dim3(512), 0, stream>>>(h1t, xrw, xrl, noise, nw, w2x, scx,
                                               d_out, flag);
}

// Round 18
// 843.915 us; speedup vs baseline: 1.0436x; 1.0436x over previous
//
#include <hip/hip_runtime.h>
#include <hip/hip_bf16.h>

typedef __hip_bfloat16 bf16;
typedef unsigned short u16;
typedef __attribute__((ext_vector_type(8))) short bf16x8;
typedef __attribute__((ext_vector_type(4))) float f32x4;

__device__ __forceinline__ float b2f(bf16 v) { return __bfloat162float(v); }
__device__ __forceinline__ float b2f_u(u16 h) {
    union { unsigned u; float f; } c; c.u = ((unsigned)h) << 16; return c.f;
}
__device__ __forceinline__ u16 f2b(float v) {
    union { bf16 b; u16 u; } c; c.b = __float2bfloat16(v); return c.u;
}
__device__ __forceinline__ float lrelu(float v) { return v >= 0.f ? v : 0.2f * v; }
__device__ __forceinline__ float ldin(const void* p, size_t i, int isbf) {
    if (isbf) return b2f(((const bf16*)p)[i]);
    return ((const float*)p)[i];
}
// LDS act tile [pl][64 ci] bf16: chunk XOR-swizzled by (pl&7) -> conflict-free.
__device__ __forceinline__ bf16x8 frag(const u16* t, int pl, int chunk) {
    return *(const bf16x8*)(t + pl * 64 + ((chunk ^ (pl & 7)) << 3));
}
// async global->LDS, 16B per lane; lds dest is wave-uniform base + lane*16.
__device__ __forceinline__ void glds16(const u16* g, u16* l) {
    __builtin_amdgcn_global_load_lds(
        (const __attribute__((address_space(1))) unsigned int*)g,
        (__attribute__((address_space(3))) unsigned int*)l, 16, 0, 0);
}
#define SYNC() do { \
    asm volatile("s_waitcnt vmcnt(0)" ::: "memory"); \
    __builtin_amdgcn_s_barrier(); \
    __builtin_amdgcn_sched_barrier(0); \
} while (0)

// ---------------------------------------------------------------------------
// Probe: bf16 vs fp32 input detection.
// ---------------------------------------------------------------------------
__global__ __launch_bounds__(256)
void probe_kernel(const void* __restrict__ x, int* __restrict__ flag) {
    const int tid = threadIdx.x;
    __shared__ int bad;
    if (tid == 0) bad = 0;
    __syncthreads();
    const unsigned short* h = (const unsigned short*)x;
    for (int k = tid; k < 512; k += 256) {
        const unsigned e = (h[k] >> 7) & 0xFFu;
        if (e < 100u || e > 140u) atomicAdd(&bad, 1);
    }
    __syncthreads();
    if (tid == 0) flag[0] = (bad == 0) ? 1 : 0;
}

// ---------------------------------------------------------------------------
// Transpose: x [b][64ci][y][x] -> xrw [b][y][x][64ci] bf16 (hi; lo in fp32).
// (lo plane used only by conv2's full-precision shortcut.)
// ---------------------------------------------------------------------------
__global__ __launch_bounds__(256)
void transpose_kernel(const void* __restrict__ x, u16* __restrict__ xrw,
                      u16* __restrict__ xrl, const int* __restrict__ flag) {
    __shared__ u16 hA[4096];
    __shared__ u16 lA[4096];
    const int isbf = flag[0];
    const int xb = blockIdx.x;   // 0..3
    const int y  = blockIdx.y;   // 0..255
    const int b  = blockIdx.z;   // 0..7
    const int t  = threadIdx.x;
    const int gx0 = xb << 6;

    if (isbf) {
        const u16* xp = (const u16*)x;
        for (int i = 0; i < 2; ++i) {
            const int chunk = i * 256 + t;
            const int ci = chunk >> 3, xc = chunk & 7;
            bf16x8 v = *(const bf16x8*)(xp + (((size_t)b * 64 + ci) << 16) +
                                        ((size_t)y << 8) + gx0 + xc * 8);
#pragma unroll
            for (int j = 0; j < 8; ++j) {
                const int pl = xc * 8 + j;
                hA[pl * 64 + (ci ^ (((pl >> 3) & 7) << 3))] = (u16)v[j];
            }
        }
    } else {
        const float* xp = (const float*)x;
        for (int i = 0; i < 4; ++i) {
            const int chunk = i * 256 + t;
            const int ci = chunk >> 4, x4 = chunk & 15;
            f32x4 v = *(const f32x4*)(xp + (((size_t)b * 64 + ci) << 16) +
                                      ((size_t)y << 8) + gx0 + x4 * 4);
#pragma unroll
            for (int j = 0; j < 4; ++j) {
                const int pl = x4 * 4 + j;
                const int a = pl * 64 + (ci ^ (((pl >> 3) & 7) << 3));
                const u16 h = f2b(v[j]);
                hA[a] = h;
                lA[a] = f2b(v[j] - b2f_u(h));
            }
        }
    }
    __syncthreads();
    for (int i = 0; i < 2; ++i) {
        const int chunk = i * 256 + t;
        const int xl = chunk >> 3, co = chunk & 7;
        const int a = xl * 64 + ((co ^ ((xl >> 3) & 7)) << 3);
        const size_t dst = (((((size_t)b << 16) + ((size_t)y << 8)) + gx0 + xl) << 6) + co * 8;
        *(bf16x8*)(xrw + dst) = *(const bf16x8*)(hA + a);
        if (!isbf) *(bf16x8*)(xrl + dst) = *(const bf16x8*)(lA + a);
    }
}

// ---------------------------------------------------------------------------
// Weights: styles + demod; effective weights (bf16 hi ONLY) stored as
// per-TAP 16 KB slabs:
//   w1x: [b][9 tap][128 oc][8 ch x 16B]   ch = ((g<<1)|cs) ^ (oc&7)
//   w2x: [b][18 tap][128 oc][8 ch x 16B]  (tap = cc*9 + t; ci frag-permuted)
// ---------------------------------------------------------------------------
__global__ __launch_bounds__(256)
void weights_kernel(const void* __restrict__ s,
                    const void* __restrict__ a1w, const void* __restrict__ a1b,
                    const void* __restrict__ w1,
                    const void* __restrict__ a2w, const void* __restrict__ a2b,
                    const void* __restrict__ w2,
                    const void* __restrict__ scw_in,
                    u16* __restrict__ w1x, u16* __restrict__ w2x,
                    u16* __restrict__ scx, const int* __restrict__ flag) {
    const int isbf = flag[0];
    const int b = blockIdx.x;
    const int part = blockIdx.y;   // 0..3
    const int tid = threadIdx.x;
    __shared__ float sb[64];
    __shared__ float st1[64];
    __shared__ float st2[128];
    __shared__ float d1[128];
    __shared__ float d2[128];

    if (tid < 64) sb[tid] = ldin(s, b * 64 + tid, isbf);
    __syncthreads();

    if (tid < 64) {
        float a = ldin(a1b, tid, isbf) + 1.f;
        for (int j = 0; j < 64; ++j) a += sb[j] * ldin(a1w, tid * 64 + j, isbf);
        st1[tid] = a;
    }
    if (tid >= 128) {
        const int i = tid - 128;
        float a = ldin(a2b, i, isbf) + 1.f;
        for (int j = 0; j < 64; ++j) a += sb[j] * ldin(a2w, i * 64 + j, isbf);
        st2[i] = a;
    }
    __syncthreads();

    if (tid < 128) {
        float acc = 0.f;
        if (isbf) {
            const u16* wp = (const u16*)w1 + tid * 576;
            for (int k = 0; k < 72; ++k) {
                bf16x8 v = *(const bf16x8*)(wp + k * 8);
#pragma unroll
                for (int e = 0; e < 8; ++e) {
                    const int r = k * 8 + e;
                    const float f = b2f_u((u16)v[e]) * st1[r / 9];
                    acc += f * f;
                }
            }
        } else {
            for (int i = 0; i < 64; ++i) {
                const float st = st1[i];
                for (int t = 0; t < 9; ++t) {
                    const float v = ldin(w1, (tid * 64 + i) * 9 + t, isbf) * st;
                    acc += v * v;
                }
            }
        }
        d1[tid] = rsqrtf(acc + 1e-8f);
    } else {
        const int o = tid - 128;
        float acc = 0.f;
        if (isbf) {
            const u16* wp = (const u16*)w2 + o * 1152;
            for (int k = 0; k < 144; ++k) {
                bf16x8 v = *(const bf16x8*)(wp + k * 8);
#pragma unroll
                for (int e = 0; e < 8; ++e) {
                    const int r = k * 8 + e;
                    const float f = b2f_u((u16)v[e]) * st2[r / 9];
                    acc += f * f;
                }
            }
        } else {
            for (int i = 0; i < 128; ++i) {
                const float st = st2[i];
                for (int t = 0; t < 9; ++t) {
                    const float v = ldin(w2, (o * 128 + i) * 9 + t, isbf) * st;
                    acc += v * v;
                }
            }
        }
        d2[o] = rsqrtf(acc + 1e-8f);
    }
    __syncthreads();

    // w1x slabs (hi only, per-tap)
    for (int idx = part * 18432 + tid; idx < (part + 1) * 18432; idx += 256) {
        const int o = idx / 576;
        const int r = idx - o * 576;
        const int i = r / 9;
        const int t = r - i * 9;
        const float w = ldin(w1, idx, isbf) * st1[i] * d1[o];
        const int cs = i >> 5, g = (i >> 3) & 3, e = i & 7;
        const size_t base = (((size_t)b * 9 + t) << 13) + o * 64;
        w1x[base + (((((g << 1) | cs)) ^ (o & 7)) << 3) + e] = f2b(w);
    }
    // w2x slabs (hi only, per-tap, ci fragment-permuted)
    for (int idx = part * 36864 + tid; idx < (part + 1) * 36864; idx += 256) {
        const int o = idx / 1152;
        const int r = idx - o * 1152;
        const int i = r / 9;
        const int t = r - i * 9;
        const float w = ldin(w2, idx, isbf) * st2[i] * d2[o];
        const int ip = (i & 64) + (((i >> 2) & 3) << 4) + (((i >> 4) & 3) << 2) + (i & 3);
        const int cc = ip >> 6, p6 = ip & 63;
        const int cs = p6 >> 5, g = (p6 >> 3) & 3, e = p6 & 7;
        const int tap = cc * 9 + t;
        const size_t base = (((size_t)b * 18 + tap) << 13) + o * 64;
        w2x[base + (((((g << 1) | cs)) ^ (o & 7)) << 3) + e] = f2b(w);
    }
    // shortcut [128 oc][8 ch][hi8|lo8] (kept full precision)
    if (b == 0 && part == 0) {
        for (int idx = tid; idx < 8192; idx += 256) {
            const int o = idx >> 6, i = idx & 63;
            const float w = ldin(scw_in, idx, isbf);
            const u16 h = f2b(w);
            const size_t dst = ((size_t)o << 7) + ((i >> 3) << 4) + (i & 7);
            scx[dst] = h;
            scx[dst + 8] = f2b(w - b2f_u(h));
        }
    }
}

// ---------------------------------------------------------------------------
// Conv1 (512 thr, 8 waves = 2 oc-halves x 4 row-quarters, acc[4][4]):
// hi-only input -> 9 tap-phases in BOTH modes. Slab DMA dbuf; 74.2 KB LDS,
// 2 blocks/CU (16 waves/CU, 4/SIMD).
// ---------------------------------------------------------------------------
__global__ __launch_bounds__(512, 4)
void conv1_mfma(const u16* __restrict__ xrw,
                const void* __restrict__ noise, const void* __restrict__ nwp,
                const u16* __restrict__ w1x, u16* __restrict__ h1t,
                const int* __restrict__ flag) {
    __shared__ __align__(16) u16 lds[324 * 64 + 2 * 8192];
    u16* tile  = lds;
    u16* slab0 = lds + 20736;
    u16* slab1 = lds + 28928;
    const int isbf = flag[0];
    const int n = blockIdx.x + (blockIdx.y << 4) + (blockIdx.z << 8);
    const int sw = (n & 7) * 256 + (n >> 3);         // same-b -> same XCD
    const int b = sw >> 8;
    const int by = (sw >> 4) & 15;
    const int bx = sw & 15;
    const int gx0 = bx << 4, gy0 = by << 4;
    const int tid = threadIdx.x;
    const int lane = tid & 63;
    const int wv = tid >> 6;
    const int wm = wv >> 2, wn = wv & 3;
    const int l15 = lane & 15, g = lane >> 4;
    const int swh = (((g << 1) ^ (l15 & 7)) << 3);            // cs0 weights
    const int swl = ((((g << 1) | 1) ^ (l15 & 7)) << 3);      // cs1 weights
    const int plb = wn * 72 + l15;                   // wn*4 rows * 18 + l15

    auto stage_act = [&]() {
        for (int idx = tid; idx < 2592; idx += 512) {
            const int pl = idx >> 3, c = idx & 7;
            const int row = pl / 18, col = pl - row * 18;
            const int gy = gy0 - 1 + row, gx = gx0 - 1 + col;
            u16 ov[8];
            if ((unsigned)gy < 256u && (unsigned)gx < 256u) {
                const size_t ofs = ((((size_t)b << 16) + (gy << 8) + gx) << 6) + c * 8;
                bf16x8 vh = *(const bf16x8*)(xrw + ofs);
#pragma unroll
                for (int j = 0; j < 8; ++j) {
                    u16 h = (u16)vh[j];
                    if (h & 0x8000u) h = f2b(0.2f * b2f_u(h));
                    ov[j] = h;
                }
            } else {
#pragma unroll
                for (int j = 0; j < 8; ++j) ov[j] = 0;
            }
            *(bf16x8*)(tile + pl * 64 + ((c ^ (pl & 7)) << 3)) = *(bf16x8*)ov;
        }
    };

    auto stageW = [&](int tap, u16* slab) {
        const u16* src = w1x + (((size_t)b * 9 + tap) << 13) + wv * 1024 + lane * 8;
        u16* dst = slab + wv * 1024;
        glds16(src, dst);
        glds16(src + 512, dst + 512);
    };

    f32x4 acc[4][4];
#pragma unroll
    for (int i = 0; i < 4; ++i)
#pragma unroll
        for (int j = 0; j < 4; ++j) acc[i][j] = (f32x4){0.f, 0.f, 0.f, 0.f};

    auto mm = [&](int q, const u16* slab) {
        const int kh = q / 3, kw = q - kh * 3;
        // cs = 0 half
        {
            bf16x8 bh[4];
#pragma unroll
            for (int fn = 0; fn < 4; ++fn)
                bh[fn] = frag(tile, plb + (fn + kh) * 18 + kw, g);
            bf16x8 H[4];
#pragma unroll
            for (int fm = 0; fm < 4; ++fm)
                H[fm] = *(const bf16x8*)(slab + (wm * 64 + fm * 16 + l15) * 64 + swh);
            __builtin_amdgcn_s_setprio(1);
#pragma unroll
            for (int fm = 0; fm < 4; ++fm)
#pragma unroll
                for (int fn = 0; fn < 4; ++fn)
                    acc[fm][fn] = __builtin_amdgcn_mfma_f32_16x16x32_bf16(H[fm], bh[fn], acc[fm][fn], 0, 0, 0);
            __builtin_amdgcn_s_setprio(0);
        }
        // cs = 1 half
        {
            bf16x8 bh[4];
#pragma unroll
            for (int fn = 0; fn < 4; ++fn)
                bh[fn] = frag(tile, plb + (fn + kh) * 18 + kw, 4 + g);
            bf16x8 L[4];
#pragma unroll
            for (int fm = 0; fm < 4; ++fm)
                L[fm] = *(const bf16x8*)(slab + (wm * 64 + fm * 16 + l15) * 64 + swl);
            __builtin_amdgcn_s_setprio(1);
#pragma unroll
            for (int fm = 0; fm < 4; ++fm)
#pragma unroll
                for (int fn = 0; fn < 4; ++fn)
                    acc[fm][fn] = __builtin_amdgcn_mfma_f32_16x16x32_bf16(L[fm], bh[fn], acc[fm][fn], 0, 0, 0);
            __builtin_amdgcn_s_setprio(0);
        }
    };

    stage_act();
    stageW(0, slab0);
    __syncthreads();

#pragma unroll 1
    for (int q = 0; q < 9; ++q) {
        SYNC();
        if (q + 1 < 9) stageW(q + 1, (q & 1) ? slab0 : slab1);
        mm(q, (q & 1) ? slab1 : slab0);
    }

    const float nwv = ldin(nwp, 0, isbf);
#pragma unroll
    for (int fn = 0; fn < 4; ++fn) {
        const int gy = gy0 + wn * 4 + fn;
        const int gx = gx0 + l15;
        const float nv = nwv * ldin(noise, ((size_t)b << 16) + (gy << 8) + gx, isbf);
        unsigned wd[8];
#pragma unroll
        for (int fm = 0; fm < 4; ++fm) {
            wd[fm * 2]     = (unsigned)f2b(lrelu(acc[fm][fn][0] + nv)) |
                             ((unsigned)f2b(lrelu(acc[fm][fn][1] + nv)) << 16);
            wd[fm * 2 + 1] = (unsigned)f2b(lrelu(acc[fm][fn][2] + nv)) |
                             ((unsigned)f2b(lrelu(acc[fm][fn][3] + nv)) << 16);
        }
        u16* dst = h1t + ((((size_t)b << 16) + (gy << 8) + gx) << 7) + wm * 64 + g * 16;
        *(uint4*)dst = make_uint4(wd[0], wd[1], wd[2], wd[3]);
        *(uint4*)(dst + 8) = make_uint4(wd[4], wd[5], wd[6], wd[7]);
    }
}

// ---------------------------------------------------------------------------
// Conv2 (512 thr): conv3x3(h1, w2-hi) + full-precision 1x1 shortcut + noise,
// /sqrt2. 18 tap-phases (9 per cc half); cc1 restaged mid-loop. Shortcut hi
// tile is REGISTER-STAGED before the loop (T14: latency hides under phase 0's
// slab drain) and written to LDS only after the conv phases.
// ---------------------------------------------------------------------------
__global__ __launch_bounds__(512, 4)
void conv2_mfma(const u16* __restrict__ h1t, const u16* __restrict__ xrw,
                const u16* __restrict__ xrl,
                const void* __restrict__ noise, const void* __restrict__ nwp,
                const u16* __restrict__ w2x, const u16* __restrict__ scx,
                void* __restrict__ out, const int* __restrict__ flag) {
    __shared__ __align__(16) u16 lds[324 * 64 + 2 * 8192];
    u16* tile  = lds;
    u16* slab0 = lds + 20736;
    u16* slab1 = lds + 28928;
    u16* tsc   = slab0;                  // 32 KB spanning both slabs
    const int isbf = flag[0];
    const int n = blockIdx.x + (blockIdx.y << 4) + (blockIdx.z << 8);
    const int sw = (n & 7) * 256 + (n >> 3);
    const int b = sw >> 8;
    const int by = (sw >> 4) & 15;
    const int bx = sw & 15;
    const int gx0 = bx << 4, gy0 = by << 4;
    const int tid = threadIdx.x;
    const int lane = tid & 63;
    const int wv = tid >> 6;
    const int wm = wv >> 2, wn = wv & 3;
    const int l15 = lane & 15, g = lane >> 4;
    const int swh = (((g << 1) ^ (l15 & 7)) << 3);
    const int swl = ((((g << 1) | 1) ^ (l15 & 7)) << 3);
    const int plb = wn * 72 + l15;
    const bf16x8 z8 = {0, 0, 0, 0, 0, 0, 0, 0};

    auto stage_cc = [&](int cc) {
        for (int idx = tid; idx < 2592; idx += 512) {
            const int pl = idx >> 3, c = idx & 7;
            const int row = pl / 18, col = pl - row * 18;
            const int gy = gy0 - 1 + row, gx = gx0 - 1 + col;
            bf16x8 v = z8;
            if ((unsigned)gy < 256u && (unsigned)gx < 256u)
                v = *(const bf16x8*)(h1t + ((((size_t)b << 16) + (gy << 8) + gx) << 7) + cc * 64 + c * 8);
            *(bf16x8*)(tile + pl * 64 + ((c ^ (pl & 7)) << 3)) = v;
        }
    };
    auto stageW = [&](int tap, u16* slab) {
        const u16* src = w2x + (((size_t)b * 18 + tap) << 13) + wv * 1024 + lane * 8;
        u16* dst = slab + wv * 1024;
        glds16(src, dst);
        glds16(src + 512, dst + 512);
    };

    f32x4 acc[4][4];
#pragma unroll
    for (int i = 0; i < 4; ++i)
#pragma unroll
        for (int j = 0; j < 4; ++j) acc[i][j] = (f32x4){0.f, 0.f, 0.f, 0.f};

    auto mm = [&](int q, const u16* slab) {
        const int qq = q % 9;
        const int kh = qq / 3, kw = qq - kh * 3;
        {
            bf16x8 bh[4];
#pragma unroll
            for (int fn = 0; fn < 4; ++fn)
                bh[fn] = frag(tile, plb + (fn + kh) * 18 + kw, g);
            bf16x8 H[4];
#pragma unroll
            for (int fm = 0; fm < 4; ++fm)
                H[fm] = *(const bf16x8*)(slab + (wm * 64 + fm * 16 + l15) * 64 + swh);
            __builtin_amdgcn_s_setprio(1);
#pragma unroll
            for (int fm = 0; fm < 4; ++fm)
#pragma unroll
                for (int fn = 0; fn < 4; ++fn)
                    acc[fm][fn] = __builtin_amdgcn_mfma_f32_16x16x32_bf16(H[fm], bh[fn], acc[fm][fn], 0, 0, 0);
            __builtin_amdgcn_s_setprio(0);
        }
        {
            bf16x8 bh[4];
#pragma unroll
            for (int fn = 0; fn < 4; ++fn)
                bh[fn] = frag(tile, plb + (fn + kh) * 18 + kw, 4 + g);
            bf16x8 L[4];
#pragma unroll
            for (int fm = 0; fm < 4; ++fm)
                L[fm] = *(const bf16x8*)(slab + (wm * 64 + fm * 16 + l15) * 64 + swl);
            __builtin_amdgcn_s_setprio(1);
#pragma unroll
            for (int fm = 0; fm < 4; ++fm)
#pragma unroll
                for (int fn = 0; fn < 4; ++fn)
                    acc[fm][fn] = __builtin_amdgcn_mfma_f32_16x16x32_bf16(L[fm], bh[fn], acc[fm][fn], 0, 0, 0);
            __builtin_amdgcn_s_setprio(0);
        }
    };

    stage_cc(0);
    stageW(0, slab0);
    __syncthreads();

    // T14: issue shortcut hi loads now; latency hides under phase-0 slab drain.
    bf16x8 sc0[4];
#pragma unroll
    for (int k = 0; k < 4; ++k) {
        const int idx = tid + (k << 9);
        const int pl = idx >> 3, c = idx & 7;
        const int gy = gy0 + (pl >> 4), gx = gx0 + (pl & 15);
        sc0[k] = *(const bf16x8*)(xrw + ((((size_t)b << 16) + (gy << 8) + gx) << 6) + c * 8);
    }

#pragma unroll 1
    for (int q = 0; q < 18; ++q) {
        if (q == 9) {                    // restage cc1 act half
            __syncthreads();
            stage_cc(1);
            __syncthreads();
        }
        SYNC();
        if (q + 1 < 18) stageW(q + 1, (q & 1) ? slab0 : slab1);
        mm(q, (q & 1) ? slab1 : slab0);
    }

    // ---- 1x1 shortcut: write reg-staged hi tile into tsc (aliases slabs) ----
    auto sc_phases = [&](int dolo) {
        const u16* sB = scx + (wm * 64 + l15) * 128 + g * 16;
#pragma unroll
        for (int cs = 0; cs < 2; ++cs) {
            bf16x8 bh[4];
#pragma unroll
            for (int fn = 0; fn < 4; ++fn)
                bh[fn] = frag(tsc, (wn * 4 + fn) * 16 + l15, cs * 4 + g);
            const u16* at = sB + cs * 64;
            __builtin_amdgcn_s_setprio(1);
#pragma unroll
            for (int fm = 0; fm < 4; ++fm) {
                const bf16x8 ah = *(const bf16x8*)(at + fm * 2048);
#pragma unroll
                for (int fn = 0; fn < 4; ++fn)
                    acc[fm][fn] = __builtin_amdgcn_mfma_f32_16x16x32_bf16(ah, bh[fn], acc[fm][fn], 0, 0, 0);
                if (dolo) {
                    const bf16x8 al = *(const bf16x8*)(at + fm * 2048 + 8);
#pragma unroll
                    for (int fn = 0; fn < 4; ++fn)
                        acc[fm][fn] = __builtin_amdgcn_mfma_f32_16x16x32_bf16(al, bh[fn], acc[fm][fn], 0, 0, 0);
                }
            }
            __builtin_amdgcn_s_setprio(0);
        }
    };

    __syncthreads();          // all waves done with slab reads before overwrite
#pragma unroll
    for (int k = 0; k < 4; ++k) {
        const int idx = tid + (k << 9);
        const int pl = idx >> 3, c = idx & 7;
        *(bf16x8*)(tsc + pl * 64 + ((c ^ (pl & 7)) << 3)) = sc0[k];
    }
    __syncthreads();
    sc_phases(1);
    if (!isbf) {
        __syncthreads();
#pragma unroll
        for (int k = 0; k < 4; ++k) {
            const int idx = tid + (k << 9);
            const int pl = idx >> 3, c = idx & 7;
            const int gy = gy0 + (pl >> 4), gx = gx0 + (pl & 15);
            bf16x8 v = *(const bf16x8*)(xrl + ((((size_t)b << 16) + (gy << 8) + gx) << 6) + c * 8);
            *(bf16x8*)(tsc + pl * 64 + ((c ^ (pl & 7)) << 3)) = v;
        }
        __syncthreads();
        sc_phases(0);
    }

    const float nwv = ldin(nwp, 0, isbf);
    const float kk = 0.70710678118654752f;
    if (isbf) {
        bf16* op = (bf16*)out;
#pragma unroll
        for (int fn = 0; fn < 4; ++fn) {
            const int gy = gy0 + wn * 4 + fn;
            const int gx = gx0 + l15;
            const float nv = nwv * ldin(noise, ((size_t)b << 16) + (gy << 8) + gx, isbf);
#pragma unroll
            for (int fm = 0; fm < 4; ++fm) {
                const int oc = wm * 64 + fm * 16 + g * 4;
#pragma unroll
                for (int r = 0; r < 4; ++r) {
                    const float v = (acc[fm][fn][r] + nv) * kk;
                    op[(((size_t)b * 128 + oc + r) << 16) + (gy << 8) + gx] = __float2bfloat16(v);
                }
            }
        }
    } else {
        float* op = (float*)out;
#pragma unroll
        for (int fn = 0; fn < 4; ++fn) {
            const int gy = gy0 + wn * 4 + fn;
            const int gx = gx0 + l15;
            const float nv = nwv * ldin(noise, ((size_t)b << 16) + (gy << 8) + gx, isbf);
#pragma unroll
            for (int fm = 0; fm < 4; ++fm) {
                const int oc = wm * 64 + fm * 16 + g * 4;
#pragma unroll
                for (int r = 0; r < 4; ++r) {
                    const float v = (acc[fm][fn][r] + nv) * kk;
                    op[(((size_t)b * 128 + oc + r) << 16) + (gy << 8) + gx] = v;
                }
            }
        }
    }
}

extern "C" void kernel_launch(void* const* d_in, const int* in_sizes, int n_in,
                              void* d_out, int out_size, void* d_ws, size_t ws_size,
                              hipStream_t stream) {
    const void* x     = d_in[0];
    const void* s     = d_in[1];
    const void* noise = d_in[2];
    const void* a1w   = d_in[3];
    const void* a1b   = d_in[4];
    const void* w1    = d_in[5];
    const void* a2w   = d_in[6];
    const void* a2b   = d_in[7];
    const void* w2    = d_in[8];
    const void* nw    = d_in[9];
    const void* scw   = d_in[10];

    // ws layout (bytes):
    //   flag      256
    //   w1x       1,179,648   ([8][9 tap][16 KB slab], hi only)
    //   w2x       2,359,296   ([8][18 tap][16 KB slab], hi only)
    //   scx          32,768
    //   h1t     134,217,728   ([8][256][256][128] bf16, permuted oc)
    //   xrw      67,108,864   ([8][256][256][64] bf16, raw hi)
    //   xrl      67,108,864   (lo plane; fp32 mode, shortcut only)
    char* p = (char*)d_ws;
    int* flag = (int*)p;   p += 256;
    u16* w1x = (u16*)p;    p += 1179648;
    u16* w2x = (u16*)p;    p += 2359296;
    u16* scx = (u16*)p;    p += 32768;
    u16* h1t = (u16*)p;    p += 134217728;
    u16* xrw = (u16*)p;    p += 67108864;
    u16* xrl = (u16*)p;

    probe_kernel<<<dim3(1), dim3(256), 0, stream>>>(x, flag);
    transpose_kernel<<<dim3(4, 256, 8), dim3(256), 0, stream>>>(x, xrw, xrl, flag);
    weights_kernel<<<dim3(8, 4), dim3(256), 0, stream>>>(s, a1w, a1b, w1, a2w, a2b, w2,
                                                         scw, w1x, w2x, scx, flag);
    dim3 grid(16, 16, 8);
    conv1_mfma<<<grid, dim3(512), 0, stream>>>(xrw, noise, nw, w1x, h1t, flag);
    conv2_mfma<<<grid, dim3(512), 0, stream>>>(h1t, xrw, xrl, noise, nw, w2x, scx,
                                               d_out, flag);
}

// Round 19
// 810.307 us; speedup vs baseline: 1.0869x; 1.0415x over previous
//
#include <hip/hip_runtime.h>
#include <hip/hip_bf16.h>

typedef __hip_bfloat16 bf16;
typedef unsigned short u16;
typedef __attribute__((ext_vector_type(8))) short bf16x8;
typedef __attribute__((ext_vector_type(4))) float f32x4;

__device__ __forceinline__ float b2f(bf16 v) { return __bfloat162float(v); }
__device__ __forceinline__ float b2f_u(u16 h) {
    union { unsigned u; float f; } c; c.u = ((unsigned)h) << 16; return c.f;
}
__device__ __forceinline__ u16 f2b(float v) {
    union { bf16 b; u16 u; } c; c.b = __float2bfloat16(v); return c.u;
}
__device__ __forceinline__ float lrelu(float v) { return v >= 0.f ? v : 0.2f * v; }
__device__ __forceinline__ float ldin(const void* p, size_t i, int isbf) {
    if (isbf) return b2f(((const bf16*)p)[i]);
    return ((const float*)p)[i];
}
// LDS act tile [pl][64 ci] bf16: chunk XOR-swizzled by (pl&7) -> conflict-free.
__device__ __forceinline__ bf16x8 frag(const u16* t, int pl, int chunk) {
    return *(const bf16x8*)(t + pl * 64 + ((chunk ^ (pl & 7)) << 3));
}
// async global->LDS, 16B per lane; lds dest is wave-uniform base + lane*16.
__device__ __forceinline__ void glds16(const u16* g, u16* l) {
    __builtin_amdgcn_global_load_lds(
        (const __attribute__((address_space(1))) unsigned int*)g,
        (__attribute__((address_space(3))) unsigned int*)l, 16, 0, 0);
}
#define SYNC() do { \
    asm volatile("s_waitcnt vmcnt(0)" ::: "memory"); \
    __builtin_amdgcn_s_barrier(); \
    __builtin_amdgcn_sched_barrier(0); \
} while (0)

// ---------------------------------------------------------------------------
// Probe: bf16 vs fp32 input detection.
// ---------------------------------------------------------------------------
__global__ __launch_bounds__(256)
void probe_kernel(const void* __restrict__ x, int* __restrict__ flag) {
    const int tid = threadIdx.x;
    __shared__ int bad;
    if (tid == 0) bad = 0;
    __syncthreads();
    const unsigned short* h = (const unsigned short*)x;
    for (int k = tid; k < 512; k += 256) {
        const unsigned e = (h[k] >> 7) & 0xFFu;
        if (e < 100u || e > 140u) atomicAdd(&bad, 1);
    }
    __syncthreads();
    if (tid == 0) flag[0] = (bad == 0) ? 1 : 0;
}

// ---------------------------------------------------------------------------
// Transpose: x [b][64ci][y][x] -> xrw [b][y][x][64ci] bf16 (hi; lo in fp32).
// (lo plane used only by conv2's full-precision shortcut.)
// ---------------------------------------------------------------------------
__global__ __launch_bounds__(256)
void transpose_kernel(const void* __restrict__ x, u16* __restrict__ xrw,
                      u16* __restrict__ xrl, const int* __restrict__ flag) {
    __shared__ u16 hA[4096];
    __shared__ u16 lA[4096];
    const int isbf = flag[0];
    const int xb = blockIdx.x;   // 0..3
    const int y  = blockIdx.y;   // 0..255
    const int b  = blockIdx.z;   // 0..7
    const int t  = threadIdx.x;
    const int gx0 = xb << 6;

    if (isbf) {
        const u16* xp = (const u16*)x;
        for (int i = 0; i < 2; ++i) {
            const int chunk = i * 256 + t;
            const int ci = chunk >> 3, xc = chunk & 7;
            bf16x8 v = *(const bf16x8*)(xp + (((size_t)b * 64 + ci) << 16) +
                                        ((size_t)y << 8) + gx0 + xc * 8);
#pragma unroll
            for (int j = 0; j < 8; ++j) {
                const int pl = xc * 8 + j;
                hA[pl * 64 + (ci ^ (((pl >> 3) & 7) << 3))] = (u16)v[j];
            }
        }
    } else {
        const float* xp = (const float*)x;
        for (int i = 0; i < 4; ++i) {
            const int chunk = i * 256 + t;
            const int ci = chunk >> 4, x4 = chunk & 15;
            f32x4 v = *(const f32x4*)(xp + (((size_t)b * 64 + ci) << 16) +
                                      ((size_t)y << 8) + gx0 + x4 * 4);
#pragma unroll
            for (int j = 0; j < 4; ++j) {
                const int pl = x4 * 4 + j;
                const int a = pl * 64 + (ci ^ (((pl >> 3) & 7) << 3));
                const u16 h = f2b(v[j]);
                hA[a] = h;
                lA[a] = f2b(v[j] - b2f_u(h));
            }
        }
    }
    __syncthreads();
    for (int i = 0; i < 2; ++i) {
        const int chunk = i * 256 + t;
        const int xl = chunk >> 3, co = chunk & 7;
        const int a = xl * 64 + ((co ^ ((xl >> 3) & 7)) << 3);
        const size_t dst = (((((size_t)b << 16) + ((size_t)y << 8)) + gx0 + xl) << 6) + co * 8;
        *(bf16x8*)(xrw + dst) = *(const bf16x8*)(hA + a);
        if (!isbf) *(bf16x8*)(xrl + dst) = *(const bf16x8*)(lA + a);
    }
}

// ---------------------------------------------------------------------------
// Weights: styles + demod; effective weights (bf16 hi ONLY) stored as
// per-TAP 16 KB slabs:
//   w1x: [b][9 tap][128 oc][8 ch x 16B]   ch = ((g<<1)|cs) ^ (oc&7)
//   w2x: [b][18 tap][128 oc][8 ch x 16B]  (tap = cc*9 + t; ci frag-permuted)
// ---------------------------------------------------------------------------
__global__ __launch_bounds__(256)
void weights_kernel(const void* __restrict__ s,
                    const void* __restrict__ a1w, const void* __restrict__ a1b,
                    const void* __restrict__ w1,
                    const void* __restrict__ a2w, const void* __restrict__ a2b,
                    const void* __restrict__ w2,
                    const void* __restrict__ scw_in,
                    u16* __restrict__ w1x, u16* __restrict__ w2x,
                    u16* __restrict__ scx, const int* __restrict__ flag) {
    const int isbf = flag[0];
    const int b = blockIdx.x;
    const int part = blockIdx.y;   // 0..3
    const int tid = threadIdx.x;
    __shared__ float sb[64];
    __shared__ float st1[64];
    __shared__ float st2[128];
    __shared__ float d1[128];
    __shared__ float d2[128];

    if (tid < 64) sb[tid] = ldin(s, b * 64 + tid, isbf);
    __syncthreads();

    if (tid < 64) {
        float a = ldin(a1b, tid, isbf) + 1.f;
        for (int j = 0; j < 64; ++j) a += sb[j] * ldin(a1w, tid * 64 + j, isbf);
        st1[tid] = a;
    }
    if (tid >= 128) {
        const int i = tid - 128;
        float a = ldin(a2b, i, isbf) + 1.f;
        for (int j = 0; j < 64; ++j) a += sb[j] * ldin(a2w, i * 64 + j, isbf);
        st2[i] = a;
    }
    __syncthreads();

    if (tid < 128) {
        float acc = 0.f;
        if (isbf) {
            const u16* wp = (const u16*)w1 + tid * 576;
            for (int k = 0; k < 72; ++k) {
                bf16x8 v = *(const bf16x8*)(wp + k * 8);
#pragma unroll
                for (int e = 0; e < 8; ++e) {
                    const int r = k * 8 + e;
                    const float f = b2f_u((u16)v[e]) * st1[r / 9];
                    acc += f * f;
                }
            }
        } else {
            for (int i = 0; i < 64; ++i) {
                const float st = st1[i];
                for (int t = 0; t < 9; ++t) {
                    const float v = ldin(w1, (tid * 64 + i) * 9 + t, isbf) * st;
                    acc += v * v;
                }
            }
        }
        d1[tid] = rsqrtf(acc + 1e-8f);
    } else {
        const int o = tid - 128;
        float acc = 0.f;
        if (isbf) {
            const u16* wp = (const u16*)w2 + o * 1152;
            for (int k = 0; k < 144; ++k) {
                bf16x8 v = *(const bf16x8*)(wp + k * 8);
#pragma unroll
                for (int e = 0; e < 8; ++e) {
                    const int r = k * 8 + e;
                    const float f = b2f_u((u16)v[e]) * st2[r / 9];
                    acc += f * f;
                }
            }
        } else {
            for (int i = 0; i < 128; ++i) {
                const float st = st2[i];
                for (int t = 0; t < 9; ++t) {
                    const float v = ldin(w2, (o * 128 + i) * 9 + t, isbf) * st;
                    acc += v * v;
                }
            }
        }
        d2[o] = rsqrtf(acc + 1e-8f);
    }
    __syncthreads();

    // w1x slabs (hi only, per-tap)
    for (int idx = part * 18432 + tid; idx < (part + 1) * 18432; idx += 256) {
        const int o = idx / 576;
        const int r = idx - o * 576;
        const int i = r / 9;
        const int t = r - i * 9;
        const float w = ldin(w1, idx, isbf) * st1[i] * d1[o];
        const int cs = i >> 5, g = (i >> 3) & 3, e = i & 7;
        const size_t base = (((size_t)b * 9 + t) << 13) + o * 64;
        w1x[base + (((((g << 1) | cs)) ^ (o & 7)) << 3) + e] = f2b(w);
    }
    // w2x slabs (hi only, per-tap, ci fragment-permuted)
    for (int idx = part * 36864 + tid; idx < (part + 1) * 36864; idx += 256) {
        const int o = idx / 1152;
        const int r = idx - o * 1152;
        const int i = r / 9;
        const int t = r - i * 9;
        const float w = ldin(w2, idx, isbf) * st2[i] * d2[o];
        const int ip = (i & 64) + (((i >> 2) & 3) << 4) + (((i >> 4) & 3) << 2) + (i & 3);
        const int cc = ip >> 6, p6 = ip & 63;
        const int cs = p6 >> 5, g = (p6 >> 3) & 3, e = p6 & 7;
        const int tap = cc * 9 + t;
        const size_t base = (((size_t)b * 18 + tap) << 13) + o * 64;
        w2x[base + (((((g << 1) | cs)) ^ (o & 7)) << 3) + e] = f2b(w);
    }
    // shortcut [128 oc][8 ch][hi8|lo8] (kept full precision)
    if (b == 0 && part == 0) {
        for (int idx = tid; idx < 8192; idx += 256) {
            const int o = idx >> 6, i = idx & 63;
            const float w = ldin(scw_in, idx, isbf);
            const u16 h = f2b(w);
            const size_t dst = ((size_t)o << 7) + ((i >> 3) << 4) + (i & 7);
            scx[dst] = h;
            scx[dst + 8] = f2b(w - b2f_u(h));
        }
    }
}

// ---------------------------------------------------------------------------
// Conv1 (512 thr, 8 waves = 2 oc-halves x 4 row-quarters, acc[4][4]):
// hi-only input -> 9 tap-phases in BOTH modes (x-lo dropped: error is far
// below the bf16-h1 floor). Slab DMA dbuf; 74.2 KB LDS, 2 blocks/CU.
// ---------------------------------------------------------------------------
__global__ __launch_bounds__(512, 4)
void conv1_mfma(const u16* __restrict__ xrw,
                const void* __restrict__ noise, const void* __restrict__ nwp,
                const u16* __restrict__ w1x, u16* __restrict__ h1t,
                const int* __restrict__ flag) {
    __shared__ __align__(16) u16 lds[324 * 64 + 2 * 8192];
    u16* tile  = lds;
    u16* slab0 = lds + 20736;
    u16* slab1 = lds + 28928;
    const int isbf = flag[0];
    const int n = blockIdx.x + (blockIdx.y << 4) + (blockIdx.z << 8);
    const int sw = (n & 7) * 256 + (n >> 3);         // same-b -> same XCD
    const int b = sw >> 8;
    const int by = (sw >> 4) & 15;
    const int bx = sw & 15;
    const int gx0 = bx << 4, gy0 = by << 4;
    const int tid = threadIdx.x;
    const int lane = tid & 63;
    const int wv = tid >> 6;
    const int wm = wv >> 2, wn = wv & 3;
    const int l15 = lane & 15, g = lane >> 4;
    const int swh = (((g << 1) ^ (l15 & 7)) << 3);            // cs0 weights
    const int swl = ((((g << 1) | 1) ^ (l15 & 7)) << 3);      // cs1 weights
    const int plb = wn * 72 + l15;                   // wn*4 rows * 18 + l15

    auto stage_act = [&]() {
        for (int idx = tid; idx < 2592; idx += 512) {
            const int pl = idx >> 3, c = idx & 7;
            const int row = pl / 18, col = pl - row * 18;
            const int gy = gy0 - 1 + row, gx = gx0 - 1 + col;
            u16 ov[8];
            if ((unsigned)gy < 256u && (unsigned)gx < 256u) {
                const size_t ofs = ((((size_t)b << 16) + (gy << 8) + gx) << 6) + c * 8;
                bf16x8 vh = *(const bf16x8*)(xrw + ofs);
#pragma unroll
                for (int j = 0; j < 8; ++j) {
                    u16 h = (u16)vh[j];
                    if (h & 0x8000u) h = f2b(0.2f * b2f_u(h));
                    ov[j] = h;
                }
            } else {
#pragma unroll
                for (int j = 0; j < 8; ++j) ov[j] = 0;
            }
            *(bf16x8*)(tile + pl * 64 + ((c ^ (pl & 7)) << 3)) = *(bf16x8*)ov;
        }
    };

    auto stageW = [&](int tap, u16* slab) {
        const u16* src = w1x + (((size_t)b * 9 + tap) << 13) + wv * 1024 + lane * 8;
        u16* dst = slab + wv * 1024;
        glds16(src, dst);
        glds16(src + 512, dst + 512);
    };

    f32x4 acc[4][4];
#pragma unroll
    for (int i = 0; i < 4; ++i)
#pragma unroll
        for (int j = 0; j < 4; ++j) acc[i][j] = (f32x4){0.f, 0.f, 0.f, 0.f};

    auto mm = [&](int q, const u16* slab) {
        const int kh = q / 3, kw = q - kh * 3;
        // cs = 0 half
        {
            bf16x8 bh[4];
#pragma unroll
            for (int fn = 0; fn < 4; ++fn)
                bh[fn] = frag(tile, plb + (fn + kh) * 18 + kw, g);
            bf16x8 H[4];
#pragma unroll
            for (int fm = 0; fm < 4; ++fm)
                H[fm] = *(const bf16x8*)(slab + (wm * 64 + fm * 16 + l15) * 64 + swh);
            __builtin_amdgcn_s_setprio(1);
#pragma unroll
            for (int fm = 0; fm < 4; ++fm)
#pragma unroll
                for (int fn = 0; fn < 4; ++fn)
                    acc[fm][fn] = __builtin_amdgcn_mfma_f32_16x16x32_bf16(H[fm], bh[fn], acc[fm][fn], 0, 0, 0);
            __builtin_amdgcn_s_setprio(0);
        }
        // cs = 1 half
        {
            bf16x8 bh[4];
#pragma unroll
            for (int fn = 0; fn < 4; ++fn)
                bh[fn] = frag(tile, plb + (fn + kh) * 18 + kw, 4 + g);
            bf16x8 L[4];
#pragma unroll
            for (int fm = 0; fm < 4; ++fm)
                L[fm] = *(const bf16x8*)(slab + (wm * 64 + fm * 16 + l15) * 64 + swl);
            __builtin_amdgcn_s_setprio(1);
#pragma unroll
            for (int fm = 0; fm < 4; ++fm)
#pragma unroll
                for (int fn = 0; fn < 4; ++fn)
                    acc[fm][fn] = __builtin_amdgcn_mfma_f32_16x16x32_bf16(L[fm], bh[fn], acc[fm][fn], 0, 0, 0);
            __builtin_amdgcn_s_setprio(0);
        }
    };

    stage_act();
    stageW(0, slab0);
    __syncthreads();

#pragma unroll 1
    for (int q = 0; q < 9; ++q) {
        SYNC();
        if (q + 1 < 9) stageW(q + 1, (q & 1) ? slab0 : slab1);
        mm(q, (q & 1) ? slab1 : slab0);
    }

    const float nwv = ldin(nwp, 0, isbf);
#pragma unroll
    for (int fn = 0; fn < 4; ++fn) {
        const int gy = gy0 + wn * 4 + fn;
        const int gx = gx0 + l15;
        const float nv = nwv * ldin(noise, ((size_t)b << 16) + (gy << 8) + gx, isbf);
        unsigned wd[8];
#pragma unroll
        for (int fm = 0; fm < 4; ++fm) {
            wd[fm * 2]     = (unsigned)f2b(lrelu(acc[fm][fn][0] + nv)) |
                             ((unsigned)f2b(lrelu(acc[fm][fn][1] + nv)) << 16);
            wd[fm * 2 + 1] = (unsigned)f2b(lrelu(acc[fm][fn][2] + nv)) |
                             ((unsigned)f2b(lrelu(acc[fm][fn][3] + nv)) << 16);
        }
        u16* dst = h1t + ((((size_t)b << 16) + (gy << 8) + gx) << 7) + wm * 64 + g * 16;
        *(uint4*)dst = make_uint4(wd[0], wd[1], wd[2], wd[3]);
        *(uint4*)(dst + 8) = make_uint4(wd[4], wd[5], wd[6], wd[7]);
    }
}

// ---------------------------------------------------------------------------
// Conv2 (512 thr): conv3x3(h1, w2-hi) + full-precision 1x1 shortcut + noise,
// /sqrt2. 18 tap-phases (9 per cc half); cc1 restaged mid-loop; shortcut
// aliases the slab area after the loop.
// ---------------------------------------------------------------------------
__global__ __launch_bounds__(512, 4)
void conv2_mfma(const u16* __restrict__ h1t, const u16* __restrict__ xrw,
                const u16* __restrict__ xrl,
                const void* __restrict__ noise, const void* __restrict__ nwp,
                const u16* __restrict__ w2x, const u16* __restrict__ scx,
                void* __restrict__ out, const int* __restrict__ flag) {
    __shared__ __align__(16) u16 lds[324 * 64 + 2 * 8192];
    u16* tile  = lds;
    u16* slab0 = lds + 20736;
    u16* slab1 = lds + 28928;
    u16* tsc   = slab0;                  // 32 KB spanning both slabs
    const int isbf = flag[0];
    const int n = blockIdx.x + (blockIdx.y << 4) + (blockIdx.z << 8);
    const int sw = (n & 7) * 256 + (n >> 3);
    const int b = sw >> 8;
    const int by = (sw >> 4) & 15;
    const int bx = sw & 15;
    const int gx0 = bx << 4, gy0 = by << 4;
    const int tid = threadIdx.x;
    const int lane = tid & 63;
    const int wv = tid >> 6;
    const int wm = wv >> 2, wn = wv & 3;
    const int l15 = lane & 15, g = lane >> 4;
    const int swh = (((g << 1) ^ (l15 & 7)) << 3);
    const int swl = ((((g << 1) | 1) ^ (l15 & 7)) << 3);
    const int plb = wn * 72 + l15;
    const bf16x8 z8 = {0, 0, 0, 0, 0, 0, 0, 0};

    auto stage_cc = [&](int cc) {
        for (int idx = tid; idx < 2592; idx += 512) {
            const int pl = idx >> 3, c = idx & 7;
            const int row = pl / 18, col = pl - row * 18;
            const int gy = gy0 - 1 + row, gx = gx0 - 1 + col;
            bf16x8 v = z8;
            if ((unsigned)gy < 256u && (unsigned)gx < 256u)
                v = *(const bf16x8*)(h1t + ((((size_t)b << 16) + (gy << 8) + gx) << 7) + cc * 64 + c * 8);
            *(bf16x8*)(tile + pl * 64 + ((c ^ (pl & 7)) << 3)) = v;
        }
    };
    auto stageW = [&](int tap, u16* slab) {
        const u16* src = w2x + (((size_t)b * 18 + tap) << 13) + wv * 1024 + lane * 8;
        u16* dst = slab + wv * 1024;
        glds16(src, dst);
        glds16(src + 512, dst + 512);
    };

    f32x4 acc[4][4];
#pragma unroll
    for (int i = 0; i < 4; ++i)
#pragma unroll
        for (int j = 0; j < 4; ++j) acc[i][j] = (f32x4){0.f, 0.f, 0.f, 0.f};

    auto mm = [&](int q, const u16* slab) {
        const int qq = q % 9;
        const int kh = qq / 3, kw = qq - kh * 3;
        {
            bf16x8 bh[4];
#pragma unroll
            for (int fn = 0; fn < 4; ++fn)
                bh[fn] = frag(tile, plb + (fn + kh) * 18 + kw, g);
            bf16x8 H[4];
#pragma unroll
            for (int fm = 0; fm < 4; ++fm)
                H[fm] = *(const bf16x8*)(slab + (wm * 64 + fm * 16 + l15) * 64 + swh);
            __builtin_amdgcn_s_setprio(1);
#pragma unroll
            for (int fm = 0; fm < 4; ++fm)
#pragma unroll
                for (int fn = 0; fn < 4; ++fn)
                    acc[fm][fn] = __builtin_amdgcn_mfma_f32_16x16x32_bf16(H[fm], bh[fn], acc[fm][fn], 0, 0, 0);
            __builtin_amdgcn_s_setprio(0);
        }
        {
            bf16x8 bh[4];
#pragma unroll
            for (int fn = 0; fn < 4; ++fn)
                bh[fn] = frag(tile, plb + (fn + kh) * 18 + kw, 4 + g);
            bf16x8 L[4];
#pragma unroll
            for (int fm = 0; fm < 4; ++fm)
                L[fm] = *(const bf16x8*)(slab + (wm * 64 + fm * 16 + l15) * 64 + swl);
            __builtin_amdgcn_s_setprio(1);
#pragma unroll
            for (int fm = 0; fm < 4; ++fm)
#pragma unroll
                for (int fn = 0; fn < 4; ++fn)
                    acc[fm][fn] = __builtin_amdgcn_mfma_f32_16x16x32_bf16(L[fm], bh[fn], acc[fm][fn], 0, 0, 0);
            __builtin_amdgcn_s_setprio(0);
        }
    };

    stage_cc(0);
    stageW(0, slab0);
    __syncthreads();

#pragma unroll 1
    for (int q = 0; q < 18; ++q) {
        if (q == 9) {                    // restage cc1 act half
            __syncthreads();
            stage_cc(1);
            __syncthreads();
        }
        SYNC();
        if (q + 1 < 18) stageW(q + 1, (q & 1) ? slab0 : slab1);
        mm(q, (q & 1) ? slab1 : slab0);
    }

    // ---- 1x1 shortcut: stage raw x into tsc (aliases slabs, 32 KB) ----
    auto stage_sc = [&](const u16* src) {
#pragma unroll
        for (int k = 0; k < 4; ++k) {
            const int idx = tid + (k << 9);
            const int pl = idx >> 3, c = idx & 7;
            const int gy = gy0 + (pl >> 4), gx = gx0 + (pl & 15);
            bf16x8 v = *(const bf16x8*)(src + ((((size_t)b << 16) + (gy << 8) + gx) << 6) + c * 8);
            *(bf16x8*)(tsc + pl * 64 + ((c ^ (pl & 7)) << 3)) = v;
        }
    };
    auto sc_phases = [&](int dolo) {
        const u16* sB = scx + (wm * 64 + l15) * 128 + g * 16;
#pragma unroll
        for (int cs = 0; cs < 2; ++cs) {
            bf16x8 bh[4];
#pragma unroll
            for (int fn = 0; fn < 4; ++fn)
                bh[fn] = frag(tsc, (wn * 4 + fn) * 16 + l15, cs * 4 + g);
            const u16* at = sB + cs * 64;
            __builtin_amdgcn_s_setprio(1);
#pragma unroll
            for (int fm = 0; fm < 4; ++fm) {
                const bf16x8 ah = *(const bf16x8*)(at + fm * 2048);
#pragma unroll
                for (int fn = 0; fn < 4; ++fn)
                    acc[fm][fn] = __builtin_amdgcn_mfma_f32_16x16x32_bf16(ah, bh[fn], acc[fm][fn], 0, 0, 0);
                if (dolo) {
                    const bf16x8 al = *(const bf16x8*)(at + fm * 2048 + 8);
#pragma unroll
                    for (int fn = 0; fn < 4; ++fn)
                        acc[fm][fn] = __builtin_amdgcn_mfma_f32_16x16x32_bf16(al, bh[fn], acc[fm][fn], 0, 0, 0);
                }
            }
            __builtin_amdgcn_s_setprio(0);
        }
    };

    __syncthreads();          // all waves done with slab reads before overwrite
    stage_sc(xrw);
    __syncthreads();
    sc_phases(1);
    if (!isbf) {
        __syncthreads();
        stage_sc(xrl);
        __syncthreads();
        sc_phases(0);
    }

    const float nwv = ldin(nwp, 0, isbf);
    const float kk = 0.70710678118654752f;
    if (isbf) {
        bf16* op = (bf16*)out;
#pragma unroll
        for (int fn = 0; fn < 4; ++fn) {
            const int gy = gy0 + wn * 4 + fn;
            const int gx = gx0 + l15;
            const float nv = nwv * ldin(noise, ((size_t)b << 16) + (gy << 8) + gx, isbf);
#pragma unroll
            for (int fm = 0; fm < 4; ++fm) {
                const int oc = wm * 64 + fm * 16 + g * 4;
#pragma unroll
                for (int r = 0; r < 4; ++r) {
                    const float v = (acc[fm][fn][r] + nv) * kk;
                    op[(((size_t)b * 128 + oc + r) << 16) + (gy << 8) + gx] = __float2bfloat16(v);
                }
            }
        }
    } else {
        float* op = (float*)out;
#pragma unroll
        for (int fn = 0; fn < 4; ++fn) {
            const int gy = gy0 + wn * 4 + fn;
            const int gx = gx0 + l15;
            const float nv = nwv * ldin(noise, ((size_t)b << 16) + (gy << 8) + gx, isbf);
#pragma unroll
            for (int fm = 0; fm < 4; ++fm) {
                const int oc = wm * 64 + fm * 16 + g * 4;
#pragma unroll
                for (int r = 0; r < 4; ++r) {
                    const float v = (acc[fm][fn][r] + nv) * kk;
                    op[(((size_t)b * 128 + oc + r) << 16) + (gy << 8) + gx] = v;
                }
            }
        }
    }
}

extern "C" void kernel_launch(void* const* d_in, const int* in_sizes, int n_in,
                              void* d_out, int out_size, void* d_ws, size_t ws_size,
                              hipStream_t stream) {
    const void* x     = d_in[0];
    const void* s     = d_in[1];
    const void* noise = d_in[2];
    const void* a1w   = d_in[3];
    const void* a1b   = d_in[4];
    const void* w1    = d_in[5];
    const void* a2w   = d_in[6];
    const void* a2b   = d_in[7];
    const void* w2    = d_in[8];
    const void* nw    = d_in[9];
    const void* scw   = d_in[10];

    // ws layout (bytes):
    //   flag      256
    //   w1x       1,179,648   ([8][9 tap][16 KB slab], hi only)
    //   w2x       2,359,296   ([8][18 tap][16 KB slab], hi only)
    //   scx          32,768
    //   h1t     134,217,728   ([8][256][256][128] bf16, permuted oc)
    //   xrw      67,108,864   ([8][256][256][64] bf16, raw hi)
    //   xrl      67,108,864   (lo plane; fp32 mode, shortcut only)
    char* p = (char*)d_ws;
    int* flag = (int*)p;   p += 256;
    u16* w1x = (u16*)p;    p += 1179648;
    u16* w2x = (u16*)p;    p += 2359296;
    u16* scx = (u16*)p;    p += 32768;
    u16* h1t = (u16*)p;    p += 134217728;
    u16* xrw = (u16*)p;    p += 67108864;
    u16* xrl = (u16*)p;

    probe_kernel<<<dim3(1), dim3(256), 0, stream>>>(x, flag);
    transpose_kernel<<<dim3(4, 256, 8), dim3(256), 0, stream>>>(x, xrw, xrl, flag);
    weights_kernel<<<dim3(8, 4), dim3(256), 0, stream>>>(s, a1w, a1b, w1, a2w, a2b, w2,
                                                         scw, w1x, w2x, scx, flag);
    dim3 grid(16, 16, 8);
    conv1_mfma<<<grid, dim3(512), 0, stream>>>(xrw, noise, nw, w1x, h1t, flag);
    conv2_mfma<<<grid, dim3(512), 0, stream>>>(h1t, xrw, xrl, noise, nw, w2x, scx,
                                               d_out, flag);
}